// Round 1
// baseline (316.824 us; speedup 1.0000x reference)
//
#include <hip/hip_runtime.h>
#include <math.h>

#define TKK 512
#define TQQ 128
#define BB  8
#define EE  128
#define DD  82
#define IND 41
#define HH  128
#define G3  384
#define NL  50
#define OD  40

__device__ __forceinline__ float readlane_f(float v, int l) {
  return __int_as_float(__builtin_amdgcn_readlane(__float_as_int(v), l));
}

// ---------------- Kernel A: time embeddings + K/Q projections ----------------
// rows [0,4096): k-side (e1 params, Wk);  rows [4096,4224): q-side (e2, Wq)
__global__ void embed_project(const float* __restrict__ time_steps,
                              const float* __restrict__ query,
                              const float* __restrict__ e1_wp, const float* __restrict__ e1_bp,
                              const float* __restrict__ e1_wl, const float* __restrict__ e1_bl,
                              const float* __restrict__ e2_wp, const float* __restrict__ e2_bp,
                              const float* __restrict__ e2_wl, const float* __restrict__ e2_bl,
                              const float* __restrict__ Wk, const float* __restrict__ bk,
                              const float* __restrict__ Wq, const float* __restrict__ bq,
                              float* __restrict__ kproj, float* __restrict__ qproj) {
  __shared__ float emb[EE];
  int row = blockIdx.x;
  int e = threadIdx.x;
  float t; const float *wp, *bp, *wl, *bl, *W, *bias; float* out;
  if (row < BB * TKK) {
    t = time_steps[row];
    wp = e1_wp; bp = e1_bp; wl = e1_wl; bl = e1_bl; W = Wk; bias = bk;
    out = kproj + (size_t)row * EE;
  } else {
    int qi = row - BB * TKK;
    t = query[qi];
    wp = e2_wp; bp = e2_bp; wl = e2_wl; bl = e2_bl; W = Wq; bias = bq;
    out = qproj + (size_t)qi * EE;
  }
  emb[e] = (e == 0) ? (t * wl[0] + bl[0]) : sinf(t * wp[e - 1] + bp[e - 1]);
  __syncthreads();
  const float4* wr = (const float4*)(W + (size_t)e * EE);
  const float4* ev = (const float4*)emb;
  float acc = bias[e];
#pragma unroll 8
  for (int i = 0; i < EE / 4; i++) {
    float4 a = wr[i]; float4 c = ev[i];
    acc += a.x * c.x + a.y * c.y + a.z * c.z + a.w * c.w;
  }
  out[e] = acc;
}

// ---------------- Kernel B: masked-softmax attention + Wo projection ----------------
// One block per (b,q). att[d] = num[d]/num[41+(d%41)]; att[d>=41]==1 naturally.
__global__ void attention(const float* __restrict__ x,
                          const float* __restrict__ kproj,
                          const float* __restrict__ qproj,
                          const float* __restrict__ Wo, const float* __restrict__ bo,
                          float* __restrict__ xs) {
  __shared__ float qv[EE];
  __shared__ float w[TKK];
  __shared__ float red[8];
  __shared__ float part[2 * DD];
  __shared__ float numb[DD];
  __shared__ float attb[DD];
  int b = blockIdx.x >> 7, q = blockIdx.x & 127;
  int tid = threadIdx.x;  // 256
  if (tid < EE) qv[tid] = qproj[(size_t)q * EE + tid];
  __syncthreads();
  float lmax = -1e30f;
  for (int r = 0; r < 2; r++) {
    int k = tid + r * 256;
    const float4* kr = (const float4*)(kproj + (size_t)(b * TKK + k) * EE);
    const float4* qv4 = (const float4*)qv;
    float acc = 0.f;
#pragma unroll 8
    for (int i = 0; i < EE / 4; i++) {
      float4 a = kr[i]; float4 c = qv4[i];
      acc += a.x * c.x + a.y * c.y + a.z * c.z + a.w * c.w;
    }
    acc *= 0.08838834764831845f;  // 1/sqrt(128)
    w[k] = acc;
    lmax = fmaxf(lmax, acc);
  }
  for (int off = 32; off; off >>= 1) lmax = fmaxf(lmax, __shfl_xor(lmax, off, 64));
  if ((tid & 63) == 0) red[tid >> 6] = lmax;
  __syncthreads();
  if (tid == 0) {
    float m = red[0];
    for (int i = 1; i < 4; i++) m = fmaxf(m, red[i]);
    red[0] = m;
  }
  __syncthreads();
  float m = red[0];
  for (int r = 0; r < 2; r++) { int k = tid + r * 256; w[k] = __expf(w[k] - m); }
  __syncthreads();
  if (tid < 2 * DD) {
    int c = tid / DD, d = tid - c * DD;
    const float* xp = x + (size_t)(b * TKK + c * 256) * DD + d;
    float acc = 0.f;
#pragma unroll 4
    for (int k = 0; k < 256; k++) acc += w[c * 256 + k] * xp[(size_t)k * DD];
    part[tid] = acc;
  }
  __syncthreads();
  if (tid < DD) numb[tid] = part[tid] + part[DD + tid];
  __syncthreads();
  if (tid < DD) {
    int j = tid % IND;
    attb[tid] = numb[tid] / numb[IND + j];
  }
  __syncthreads();
  if (tid < HH) {
    const float* wo = Wo + (size_t)tid * DD;
    float acc = bo[tid];
#pragma unroll 2
    for (int d = 0; d < DD; d++) acc += wo[d] * attb[d];
    xs[((size_t)q * BB + b) * HH + tid] = acc;  // xs layout [TQ][B][H]
  }
}

// ---------------- Kernel C: precompute input gates gi for both directions ----------------
// gi layout [dir][t][b][384]
__global__ void gi_precompute(const float* __restrict__ xs,
                              const float* __restrict__ gwi_f, const float* __restrict__ gbi_f,
                              const float* __restrict__ gwi_b, const float* __restrict__ gbi_b,
                              float* __restrict__ gi) {
  __shared__ float xr[BB][EE];
  int dir = blockIdx.x >> 7, t = blockIdx.x & 127;
  const float* Wi = dir ? gwi_b : gwi_f;
  const float* bi = dir ? gbi_b : gbi_f;
  int tid = threadIdx.x;  // 384
  for (int idx = tid; idx < BB * EE; idx += G3)
    xr[idx >> 7][idx & 127] = xs[(size_t)t * BB * EE + idx];
  __syncthreads();
  const float* wr = Wi + (size_t)tid * EE;
  float bias = bi[tid];
  float acc[BB];
#pragma unroll
  for (int b = 0; b < BB; b++) acc[b] = bias;
  for (int i = 0; i < EE; i++) {
    float wv = wr[i];
#pragma unroll
    for (int b = 0; b < BB; b++) acc[b] += wv * xr[b][i];
  }
  size_t base = ((size_t)(dir * TQQ + t) * BB) * G3 + tid;
#pragma unroll
  for (int b = 0; b < BB; b++) gi[base + (size_t)b * G3] = acc[b];
}

// ---------------- Kernel D: sequential GRU (recurrent part only) ----------------
// 16 blocks = (dir, b). Thread g holds Wh row in 128 VGPRs; h broadcast via v_readlane.
__global__ __launch_bounds__(G3, 1) void gru_seq(const float* __restrict__ gi,
                                                 const float* __restrict__ gwh_f,
                                                 const float* __restrict__ gbh_f,
                                                 const float* __restrict__ gwh_b,
                                                 const float* __restrict__ gbh_b,
                                                 float* __restrict__ hcat) {
  __shared__ float gh[G3];
  __shared__ float hbuf[HH];
  int dir = blockIdx.x >> 3, b = blockIdx.x & 7;
  const float* Wh = dir ? gwh_b : gwh_f;
  const float* bh = dir ? gbh_b : gbh_f;
  int g = threadIdx.x;  // 384
  float wh[EE];
  const float4* wrow = (const float4*)(Wh + (size_t)g * EE);
#pragma unroll
  for (int c = 0; c < EE / 4; c++) {
    float4 v = wrow[c];
    wh[4 * c] = v.x; wh[4 * c + 1] = v.y; wh[4 * c + 2] = v.z; wh[4 * c + 3] = v.w;
  }
  float bias = bh[g];
  int lane = g & 63;
  float h0 = 0.f, h1 = 0.f;  // every wave holds an identical copy of h[0..127]

  for (int s = 0; s < TQQ; s++) {
    int t = dir ? (TQQ - 1 - s) : s;
    float acc = bias;
#pragma unroll
    for (int j = 0; j < 64; j++) {
      acc += wh[j]      * readlane_f(h0, j);
      acc += wh[64 + j] * readlane_f(h1, j);
    }
    gh[g] = acc;
    __syncthreads();
    if (g < HH) {
      size_t base = ((size_t)(dir * TQQ + t) * BB + b) * G3;
      float ir = gi[base + g], iz = gi[base + HH + g], inn = gi[base + 2 * HH + g];
      float hr = gh[g], hz = gh[HH + g], hn = gh[2 * HH + g];
      float r = 1.f / (1.f + __expf(-(ir + hr)));
      float z = 1.f / (1.f + __expf(-(iz + hz)));
      float n = tanhf(inn + r * hn);
      float hold = (g < 64) ? h0 : h1;
      float hnew = (1.f - z) * n + z * hold;
      hbuf[g] = hnew;
      hcat[((size_t)b * TQQ + t) * (2 * HH) + dir * HH + g] = hnew;
    }
    __syncthreads();
    h0 = hbuf[lane];
    h1 = hbuf[64 + lane];
  }
}

// ---------------- Kernel E: final MLP ----------------
__global__ void mlp_out(const float* __restrict__ hcat,
                        const float* __restrict__ W1, const float* __restrict__ b1,
                        const float* __restrict__ W2, const float* __restrict__ b2,
                        float* __restrict__ out) {
  __shared__ float hrow[2 * HH];
  __shared__ float ybuf[NL];
  int bt = blockIdx.x;      // b*128 + t
  int tid = threadIdx.x;    // 64
  for (int idx = tid; idx < 2 * HH; idx += 64) hrow[idx] = hcat[(size_t)bt * 2 * HH + idx];
  __syncthreads();
  if (tid < NL) {
    const float* wr = W1 + (size_t)tid * 2 * HH;
    float acc = b1[tid];
#pragma unroll 4
    for (int i = 0; i < 2 * HH; i++) acc += wr[i] * hrow[i];
    ybuf[tid] = fmaxf(acc, 0.f);
  }
  __syncthreads();
  if (tid < OD) {
    const float* wr = W2 + (size_t)tid * NL;
    float acc = b2[tid];
#pragma unroll 2
    for (int j = 0; j < NL; j++) acc += wr[j] * ybuf[j];
    out[(size_t)bt * OD + tid] = acc;
  }
}

extern "C" void kernel_launch(void* const* d_in, const int* in_sizes, int n_in,
                              void* d_out, int out_size, void* d_ws, size_t ws_size,
                              hipStream_t stream) {
  const float* x          = (const float*)d_in[0];
  const float* time_steps = (const float*)d_in[1];
  const float* query      = (const float*)d_in[2];
  const float* e1_wp = (const float*)d_in[3];
  const float* e1_bp = (const float*)d_in[4];
  const float* e1_wl = (const float*)d_in[5];
  const float* e1_bl = (const float*)d_in[6];
  const float* e2_wp = (const float*)d_in[7];
  const float* e2_bp = (const float*)d_in[8];
  const float* e2_wl = (const float*)d_in[9];
  const float* e2_bl = (const float*)d_in[10];
  const float* Wq = (const float*)d_in[11];
  const float* bq = (const float*)d_in[12];
  const float* Wk = (const float*)d_in[13];
  const float* bk = (const float*)d_in[14];
  const float* Wo = (const float*)d_in[15];
  const float* bo = (const float*)d_in[16];
  const float* gwi_f = (const float*)d_in[17];
  const float* gwh_f = (const float*)d_in[18];
  const float* gbi_f = (const float*)d_in[19];
  const float* gbh_f = (const float*)d_in[20];
  const float* gwi_b = (const float*)d_in[21];
  const float* gwh_b = (const float*)d_in[22];
  const float* gbi_b = (const float*)d_in[23];
  const float* gbh_b = (const float*)d_in[24];
  const float* W1 = (const float*)d_in[25];
  const float* b1 = (const float*)d_in[26];
  const float* W2 = (const float*)d_in[27];
  const float* b2 = (const float*)d_in[28];

  float* ws    = (float*)d_ws;
  float* kproj = ws;                       // 4096*128
  float* qproj = kproj + 4096 * 128;       // 128*128
  float* xs    = qproj + 128 * 128;        // 128*8*128
  float* gi    = xs + 128 * 8 * 128;       // 2*128*8*384
  float* hcat  = gi + 2 * 128 * 8 * 384;   // 8*128*256

  embed_project<<<4224, 128, 0, stream>>>(time_steps, query,
                                          e1_wp, e1_bp, e1_wl, e1_bl,
                                          e2_wp, e2_bp, e2_wl, e2_bl,
                                          Wk, bk, Wq, bq, kproj, qproj);
  attention<<<1024, 256, 0, stream>>>(x, kproj, qproj, Wo, bo, xs);
  gi_precompute<<<256, 384, 0, stream>>>(xs, gwi_f, gbi_f, gwi_b, gbi_b, gi);
  gru_seq<<<16, 384, 0, stream>>>(gi, gwh_f, gbh_f, gwh_b, gbh_b, hcat);
  mlp_out<<<1024, 64, 0, stream>>>(hcat, W1, b1, W2, b2, (float*)d_out);
}

// Round 2
// 225.983 us; speedup vs baseline: 1.4020x; 1.4020x over previous
//
#include <hip/hip_runtime.h>
#include <math.h>

#define TKK 512
#define TQQ 128
#define BB  8
#define EE  128
#define DD  82
#define IND 41
#define HH  128
#define G3  384
#define NL  50
#define OD  40

// ---------------- Kernel A: time embeddings + K/Q projections ----------------
__global__ void embed_project(const float* __restrict__ time_steps,
                              const float* __restrict__ query,
                              const float* __restrict__ e1_wp, const float* __restrict__ e1_bp,
                              const float* __restrict__ e1_wl, const float* __restrict__ e1_bl,
                              const float* __restrict__ e2_wp, const float* __restrict__ e2_bp,
                              const float* __restrict__ e2_wl, const float* __restrict__ e2_bl,
                              const float* __restrict__ Wk, const float* __restrict__ bk,
                              const float* __restrict__ Wq, const float* __restrict__ bq,
                              float* __restrict__ kproj, float* __restrict__ qproj) {
  __shared__ float emb[EE];
  int row = blockIdx.x;
  int e = threadIdx.x;
  float t; const float *wp, *bp, *wl, *bl, *W, *bias; float* out;
  if (row < BB * TKK) {
    t = time_steps[row];
    wp = e1_wp; bp = e1_bp; wl = e1_wl; bl = e1_bl; W = Wk; bias = bk;
    out = kproj + (size_t)row * EE;
  } else {
    int qi = row - BB * TKK;
    t = query[qi];
    wp = e2_wp; bp = e2_bp; wl = e2_wl; bl = e2_bl; W = Wq; bias = bq;
    out = qproj + (size_t)qi * EE;
  }
  emb[e] = (e == 0) ? (t * wl[0] + bl[0]) : sinf(t * wp[e - 1] + bp[e - 1]);
  __syncthreads();
  const float4* wr = (const float4*)(W + (size_t)e * EE);
  const float4* ev = (const float4*)emb;
  float acc = bias[e];
#pragma unroll 8
  for (int i = 0; i < EE / 4; i++) {
    float4 a = wr[i]; float4 c = ev[i];
    acc += a.x * c.x + a.y * c.y + a.z * c.z + a.w * c.w;
  }
  out[e] = acc;
}

// ---------------- Kernel B: masked-softmax attention + Wo projection ----------------
__global__ void attention(const float* __restrict__ x,
                          const float* __restrict__ kproj,
                          const float* __restrict__ qproj,
                          const float* __restrict__ Wo, const float* __restrict__ bo,
                          float* __restrict__ xs) {
  __shared__ float qv[EE];
  __shared__ float w[TKK];
  __shared__ float red[8];
  __shared__ float part[2 * DD];
  __shared__ float numb[DD];
  __shared__ float attb[DD];
  int b = blockIdx.x >> 7, q = blockIdx.x & 127;
  int tid = threadIdx.x;  // 256
  if (tid < EE) qv[tid] = qproj[(size_t)q * EE + tid];
  __syncthreads();
  float lmax = -1e30f;
  for (int r = 0; r < 2; r++) {
    int k = tid + r * 256;
    const float4* kr = (const float4*)(kproj + (size_t)(b * TKK + k) * EE);
    const float4* qv4 = (const float4*)qv;
    float acc = 0.f;
#pragma unroll 8
    for (int i = 0; i < EE / 4; i++) {
      float4 a = kr[i]; float4 c = qv4[i];
      acc += a.x * c.x + a.y * c.y + a.z * c.z + a.w * c.w;
    }
    acc *= 0.08838834764831845f;  // 1/sqrt(128)
    w[k] = acc;
    lmax = fmaxf(lmax, acc);
  }
  for (int off = 32; off; off >>= 1) lmax = fmaxf(lmax, __shfl_xor(lmax, off, 64));
  if ((tid & 63) == 0) red[tid >> 6] = lmax;
  __syncthreads();
  if (tid == 0) {
    float m = red[0];
    for (int i = 1; i < 4; i++) m = fmaxf(m, red[i]);
    red[0] = m;
  }
  __syncthreads();
  float m = red[0];
  for (int r = 0; r < 2; r++) { int k = tid + r * 256; w[k] = __expf(w[k] - m); }
  __syncthreads();
  if (tid < 2 * DD) {
    int c = tid / DD, d = tid - c * DD;
    const float* xp = x + (size_t)(b * TKK + c * 256) * DD + d;
    float acc = 0.f;
#pragma unroll 4
    for (int k = 0; k < 256; k++) acc += w[c * 256 + k] * xp[(size_t)k * DD];
    part[tid] = acc;
  }
  __syncthreads();
  if (tid < DD) numb[tid] = part[tid] + part[DD + tid];
  __syncthreads();
  if (tid < DD) {
    int j = tid % IND;
    attb[tid] = numb[tid] / numb[IND + j];
  }
  __syncthreads();
  if (tid < HH) {
    const float* wo = Wo + (size_t)tid * DD;
    float acc = bo[tid];
#pragma unroll 2
    for (int d = 0; d < DD; d++) acc += wo[d] * attb[d];
    xs[((size_t)q * BB + b) * HH + tid] = acc;  // xs layout [TQ][B][H]
  }
}

// ---------------- Kernel C: precompute input gates gi ----------------
__global__ void gi_precompute(const float* __restrict__ xs,
                              const float* __restrict__ gwi_f, const float* __restrict__ gbi_f,
                              const float* __restrict__ gwi_b, const float* __restrict__ gbi_b,
                              float* __restrict__ gi) {
  __shared__ float xr[BB][EE];
  int dir = blockIdx.x >> 7, t = blockIdx.x & 127;
  const float* Wi = dir ? gwi_b : gwi_f;
  const float* bi = dir ? gbi_b : gbi_f;
  int tid = threadIdx.x;  // 384
  for (int idx = tid; idx < BB * EE; idx += G3)
    xr[idx >> 7][idx & 127] = xs[(size_t)t * BB * EE + idx];
  __syncthreads();
  const float* wr = Wi + (size_t)tid * EE;
  float bias = bi[tid];
  float acc[BB];
#pragma unroll
  for (int b = 0; b < BB; b++) acc[b] = bias;
  for (int i = 0; i < EE; i++) {
    float wv = wr[i];
#pragma unroll
    for (int b = 0; b < BB; b++) acc[b] += wv * xr[b][i];
  }
  size_t base = ((size_t)(dir * TQQ + t) * BB) * G3 + tid;
#pragma unroll
  for (int b = 0; b < BB; b++) gi[base + (size_t)b * G3] = acc[b];
}

// ---------------- Kernel D: sequential GRU, restructured ----------------
// 16 blocks = (dir,b), 1024 threads = 16 waves.
// Thread (slice s = wave>>1, output o = (wave&1)*64+lane) computes the 3 gate
// partials for output o over K-slice [16s,16s+16), weights in VGPRs, h via
// wave-uniform ds_read_b128 broadcast. LDS reduce + pointwise tail.
__global__ __launch_bounds__(1024, 1) void gru_seq(const float* __restrict__ gi,
                                                   const float* __restrict__ gwh_f,
                                                   const float* __restrict__ gbh_f,
                                                   const float* __restrict__ gwh_b,
                                                   const float* __restrict__ gbh_b,
                                                   float* __restrict__ hcat) {
  __shared__ float part[8][3][HH];  // [slice][gate][o] — conflict-free both ways
  __shared__ float hbuf[HH];
  int dir = blockIdx.x >> 3, b = blockIdx.x & 7;
  const float* Wh = dir ? gwh_b : gwh_f;
  const float* bh = dir ? gbh_b : gbh_f;
  int tid = threadIdx.x;
  int wave = tid >> 6, lane = tid & 63;
  int s = wave >> 1;                 // 0..7, wave-uniform
  int o = ((wave & 1) << 6) | lane;  // 0..127

  // per-thread weights: rows o, 128+o, 256+o, cols [16s,16s+16)
  float4 wr4[4], wz4[4], wn4[4];
  {
    const float4* r0 = (const float4*)(Wh + (size_t)o * EE + s * 16);
    const float4* r1 = (const float4*)(Wh + (size_t)(HH + o) * EE + s * 16);
    const float4* r2 = (const float4*)(Wh + (size_t)(2 * HH + o) * EE + s * 16);
#pragma unroll
    for (int k = 0; k < 4; k++) { wr4[k] = r0[k]; wz4[k] = r1[k]; wn4[k] = r2[k]; }
  }
  float bhr = 0.f, bhz = 0.f, bhn = 0.f, hprev = 0.f;
  if (tid < HH) { bhr = bh[tid]; bhz = bh[HH + tid]; bhn = bh[2 * HH + tid]; }

  if (tid < HH) hbuf[tid] = 0.f;
  __syncthreads();

  const float4* h4p = (const float4*)hbuf;

  for (int step = 0; step < TQQ; step++) {
    int t = dir ? (TQQ - 1 - step) : step;
    // prefetch gi for the tail (hidden under matvec)
    float gir = 0.f, giz = 0.f, gin = 0.f;
    if (tid < HH) {
      size_t base = ((size_t)(dir * TQQ + t) * BB + b) * G3;
      gir = gi[base + tid]; giz = gi[base + HH + tid]; gin = gi[base + 2 * HH + tid];
    }
    // matvec partials: 4 uniform-address b128 broadcasts + 48 FMAs (6 chains)
    float pr0 = 0.f, pr1 = 0.f, pz0 = 0.f, pz1 = 0.f, pn0 = 0.f, pn1 = 0.f;
#pragma unroll
    for (int k = 0; k < 4; k++) {
      float4 h4 = h4p[s * 4 + k];
      pr0 += wr4[k].x * h4.x; pr1 += wr4[k].y * h4.y;
      pr0 += wr4[k].z * h4.z; pr1 += wr4[k].w * h4.w;
      pz0 += wz4[k].x * h4.x; pz1 += wz4[k].y * h4.y;
      pz0 += wz4[k].z * h4.z; pz1 += wz4[k].w * h4.w;
      pn0 += wn4[k].x * h4.x; pn1 += wn4[k].y * h4.y;
      pn0 += wn4[k].z * h4.z; pn1 += wn4[k].w * h4.w;
    }
    part[s][0][o] = pr0 + pr1;
    part[s][1][o] = pz0 + pz1;
    part[s][2][o] = pn0 + pn1;
    __syncthreads();
    if (tid < HH) {
      float hr = bhr, hz = bhz, hn = bhn;
#pragma unroll
      for (int ss = 0; ss < 8; ss++) {
        hr += part[ss][0][tid];
        hz += part[ss][1][tid];
        hn += part[ss][2][tid];
      }
      float r = 1.f / (1.f + __expf(-(gir + hr)));
      float z = 1.f / (1.f + __expf(-(giz + hz)));
      float a = gin + r * hn;
      float n = 1.f - 2.f / (1.f + __expf(2.f * a));  // tanh, saturation-safe
      float hnew = (1.f - z) * n + z * hprev;
      hprev = hnew;
      hbuf[tid] = hnew;
      hcat[((size_t)b * TQQ + t) * (2 * HH) + dir * HH + tid] = hnew;
    }
    __syncthreads();
  }
}

// ---------------- Kernel E: final MLP ----------------
__global__ void mlp_out(const float* __restrict__ hcat,
                        const float* __restrict__ W1, const float* __restrict__ b1,
                        const float* __restrict__ W2, const float* __restrict__ b2,
                        float* __restrict__ out) {
  __shared__ float hrow[2 * HH];
  __shared__ float ybuf[NL];
  int bt = blockIdx.x;
  int tid = threadIdx.x;  // 64
  for (int idx = tid; idx < 2 * HH; idx += 64) hrow[idx] = hcat[(size_t)bt * 2 * HH + idx];
  __syncthreads();
  if (tid < NL) {
    const float* wr = W1 + (size_t)tid * 2 * HH;
    float acc = b1[tid];
#pragma unroll 4
    for (int i = 0; i < 2 * HH; i++) acc += wr[i] * hrow[i];
    ybuf[tid] = fmaxf(acc, 0.f);
  }
  __syncthreads();
  if (tid < OD) {
    const float* wr = W2 + (size_t)tid * NL;
    float acc = b2[tid];
#pragma unroll 2
    for (int j = 0; j < NL; j++) acc += wr[j] * ybuf[j];
    out[(size_t)bt * OD + tid] = acc;
  }
}

extern "C" void kernel_launch(void* const* d_in, const int* in_sizes, int n_in,
                              void* d_out, int out_size, void* d_ws, size_t ws_size,
                              hipStream_t stream) {
  const float* x          = (const float*)d_in[0];
  const float* time_steps = (const float*)d_in[1];
  const float* query      = (const float*)d_in[2];
  const float* e1_wp = (const float*)d_in[3];
  const float* e1_bp = (const float*)d_in[4];
  const float* e1_wl = (const float*)d_in[5];
  const float* e1_bl = (const float*)d_in[6];
  const float* e2_wp = (const float*)d_in[7];
  const float* e2_bp = (const float*)d_in[8];
  const float* e2_wl = (const float*)d_in[9];
  const float* e2_bl = (const float*)d_in[10];
  const float* Wq = (const float*)d_in[11];
  const float* bq = (const float*)d_in[12];
  const float* Wk = (const float*)d_in[13];
  const float* bk = (const float*)d_in[14];
  const float* Wo = (const float*)d_in[15];
  const float* bo = (const float*)d_in[16];
  const float* gwi_f = (const float*)d_in[17];
  const float* gwh_f = (const float*)d_in[18];
  const float* gbi_f = (const float*)d_in[19];
  const float* gbh_f = (const float*)d_in[20];
  const float* gwi_b = (const float*)d_in[21];
  const float* gwh_b = (const float*)d_in[22];
  const float* gbi_b = (const float*)d_in[23];
  const float* gbh_b = (const float*)d_in[24];
  const float* W1 = (const float*)d_in[25];
  const float* b1 = (const float*)d_in[26];
  const float* W2 = (const float*)d_in[27];
  const float* b2 = (const float*)d_in[28];

  float* ws    = (float*)d_ws;
  float* kproj = ws;                       // 4096*128
  float* qproj = kproj + 4096 * 128;       // 128*128
  float* xs    = qproj + 128 * 128;        // 128*8*128
  float* gi    = xs + 128 * 8 * 128;       // 2*128*8*384
  float* hcat  = gi + 2 * 128 * 8 * 384;   // 8*128*256

  embed_project<<<4224, 128, 0, stream>>>(time_steps, query,
                                          e1_wp, e1_bp, e1_wl, e1_bl,
                                          e2_wp, e2_bp, e2_wl, e2_bl,
                                          Wk, bk, Wq, bq, kproj, qproj);
  attention<<<1024, 256, 0, stream>>>(x, kproj, qproj, Wo, bo, xs);
  gi_precompute<<<256, 384, 0, stream>>>(xs, gwi_f, gbi_f, gwi_b, gbi_b, gi);
  gru_seq<<<16, 1024, 0, stream>>>(gi, gwh_f, gbh_f, gwh_b, gbh_b, hcat);
  mlp_out<<<1024, 64, 0, stream>>>(hcat, W1, b1, W2, b2, (float*)d_out);
}